// Round 16
// baseline (249.442 us; speedup 1.0000x reference)
//
#include <hip/hip_runtime.h>

#define B_SZ 16384
#define D_SZ 1024
#define H_SZ 2048
#define C_SZ 128
#define T_STEPS 20

typedef __attribute__((ext_vector_type(4))) float f32x4;
typedef __attribute__((ext_vector_type(4))) int   i32x4;

__device__ __forceinline__ signed char to_i8(float f, float s) {
    float v = rintf(s * f);
    v = v > 127.0f ? 127.0f : (v < -127.0f ? -127.0f : v);
    return (signed char)(int)v;
}

// ---------------- W1 -> i8 frags: [p(16)][kt(16)][wr(2)][m(4)][lane(64)][16B] --------
__global__ void k_w1fragi8(const float* __restrict__ W1, signed char* __restrict__ w1f) {
    int idx = blockIdx.x * blockDim.x + threadIdx.x;   // 0..131071
    int lane = idx & 63;
    int m    = (idx >> 6) & 3;
    int wr   = (idx >> 8) & 1;
    int kt   = (idx >> 9) & 15;
    int p    = idx >> 13;
    int h = p * 128 + wr * 64 + m * 16 + (lane & 15);
    int k = kt * 64 + (lane >> 4) * 16;
    const float* src = W1 + (size_t)h * D_SZ + k;
    union { signed char b[16]; uint4 u; } q;
    #pragma unroll
    for (int q4 = 0; q4 < 4; ++q4) {
        float4 v = *reinterpret_cast<const float4*>(src + q4 * 4);
        q.b[q4 * 4 + 0] = to_i8(v.x, 1024.0f);
        q.b[q4 * 4 + 1] = to_i8(v.y, 1024.0f);
        q.b[q4 * 4 + 2] = to_i8(v.z, 1024.0f);
        q.b[q4 * 4 + 3] = to_i8(v.w, 1024.0f);
    }
    size_t off = (size_t)p * 131072 + (size_t)kt * 8192 + wr * 4096 + m * 1024 + lane * 16;
    *reinterpret_cast<uint4*>(w1f + off) = q.u;
}

// ---------------- x -> i8 frags: [bp(128)][kt(16)][wc(2)][n(4)][lane(64)][16B] -------
__global__ void k_xfragi8(const float* __restrict__ x, signed char* __restrict__ xf) {
    int idx = blockIdx.x * blockDim.x + threadIdx.x;   // 0..1048575
    int lane = idx & 63;
    int n    = (idx >> 6) & 3;
    int wc   = (idx >> 8) & 1;
    int kt   = (idx >> 9) & 15;
    int bp   = idx >> 13;
    int b = bp * 128 + wc * 64 + n * 16 + (lane & 15);
    int k = kt * 64 + (lane >> 4) * 16;
    const float* src = x + (size_t)b * D_SZ + k;
    union { signed char b[16]; uint4 u; } q;
    #pragma unroll
    for (int q4 = 0; q4 < 4; ++q4) {
        float4 v = *reinterpret_cast<const float4*>(src + q4 * 4);
        q.b[q4 * 4 + 0] = to_i8(v.x, 32.0f);
        q.b[q4 * 4 + 1] = to_i8(v.y, 32.0f);
        q.b[q4 * 4 + 2] = to_i8(v.z, 32.0f);
        q.b[q4 * 4 + 3] = to_i8(v.w, 32.0f);
    }
    size_t off = (size_t)bp * 131072 + (size_t)kt * 8192 + wc * 4096 + n * 1024 + lane * 16;
    *reinterpret_cast<uint4*>(xf + off) = q.u;
}

// ---------------- W2 -> i8 frags: [kt64(32)][nt(8)][lane(64)][16B], k-perm baked -----
__global__ void k_w2fragi8(const float* __restrict__ W2, signed char* __restrict__ w2q) {
    const int perm4[4] = {0, 2, 1, 3};
    int idx = blockIdx.x * blockDim.x + threadIdx.x;   // 0..16383
    int lane = idx & 63;
    int nt   = (idx >> 6) & 7;
    int kt   = idx >> 9;                               // 0..31
    int c = nt * 16 + (lane & 15);
    int hbase = kt * 64 + (lane >> 4) * 16;
    const float* src = W2 + (size_t)c * H_SZ + hbase;
    float f[16];
    #pragma unroll
    for (int q4 = 0; q4 < 4; ++q4) {
        float4 v = *reinterpret_cast<const float4*>(src + q4 * 4);
        f[q4 * 4 + 0] = v.x; f[q4 * 4 + 1] = v.y; f[q4 * 4 + 2] = v.z; f[q4 * 4 + 3] = v.w;
    }
    union { signed char b[16]; uint4 u; } q;
    #pragma unroll
    for (int j = 0; j < 16; ++j) {
        int k = (j & ~3) + perm4[j & 3];
        q.b[j] = to_i8(f[k], 1024.0f);
    }
    *reinterpret_cast<uint4*>(w2q + (size_t)idx * 16) = q.u;
}

// ---------------- K1: LDS-free i8 frag-GEMM (K=64) + closed-form LIF -----------------
// Register double-buffer: kt+1's 8 loads issue BEFORE kt's 16 MFMAs (no barriers ->
// prefetch shortens per-wave critical path; round-15 showed compiler kept VGPR=64
// minimal window and stalled ~200-900cyc per kt).
__global__ __launch_bounds__(256, 2) void k_gemm1_i8(
    const signed char* __restrict__ xf,
    const signed char* __restrict__ w1f,
    const float* __restrict__ b1,
    unsigned short* __restrict__ M16,
    unsigned char* __restrict__ M4,
    unsigned int* __restrict__ spike_count)
{
    __shared__ unsigned lutm[22];
    const int tid  = threadIdx.x;
    if (tid < 22) {
        unsigned m = 0;
        if (tid >= 1 && tid <= 20)
            for (int t = tid - 1; t < T_STEPS; t += tid) m |= 1u << t;
        lutm[tid] = m;
    }
    __syncthreads();

    const int wv   = tid >> 6;
    const int lane = tid & 63;
    const int l15  = lane & 15;
    const int g    = lane >> 4;
    const int wr   = wv >> 1;
    const int wc   = wv & 1;

    const int wg    = blockIdx.x;
    const int xcd   = wg & 7;
    const int local = wg >> 3;
    const int sc    = local >> 4;
    const int sl    = local & 15;
    const int b_panel = xcd * 16 + (sc >> 2) * 4 + (sl >> 2);
    const int h_idx   = (sc & 3) * 4 + (sl & 3);

    i32x4 acc[4][4];
    #pragma unroll
    for (int i = 0; i < 4; ++i)
        #pragma unroll
        for (int j = 0; j < 4; ++j)
            acc[i][j] = (i32x4){0, 0, 0, 0};

    const signed char* Ap = w1f + (size_t)h_idx * 131072 + wr * 4096 + lane * 16;
    const signed char* Bp = xf + (size_t)b_panel * 131072 + wc * 4096 + lane * 16;

    i32x4 Ar[2][4], Br[2][4];
    #pragma unroll
    for (int m = 0; m < 4; ++m) {
        Ar[0][m] = *reinterpret_cast<const i32x4*>(Ap + m * 1024);
        Br[0][m] = *reinterpret_cast<const i32x4*>(Bp + m * 1024);
    }

    #pragma unroll
    for (int kt = 0; kt < 16; ++kt) {
        const int cur = kt & 1, nxt = cur ^ 1;
        if (kt < 15) {
            #pragma unroll
            for (int m = 0; m < 4; ++m) {
                Ar[nxt][m] = *reinterpret_cast<const i32x4*>(Ap + (size_t)(kt + 1) * 8192 + m * 1024);
                Br[nxt][m] = *reinterpret_cast<const i32x4*>(Bp + (size_t)(kt + 1) * 8192 + m * 1024);
            }
        }
        #pragma unroll
        for (int m = 0; m < 4; ++m)
            #pragma unroll
            for (int n = 0; n < 4; ++n)
                acc[m][n] = __builtin_amdgcn_mfma_i32_16x16x64_i8(
                    Ar[cur][m], Br[cur][n], acc[m][n], 0, 0, 0);
    }

    int spikes = 0;
    #pragma unroll
    for (int m = 0; m < 4; ++m) {
        const int h0l = h_idx * 128 + wr * 64 + m * 16 + g * 4;
        const int kt64 = h_idx * 2 + wr;
        const int k2lane = m * 16 + l15;
        float4 bias = *reinterpret_cast<const float4*>(b1 + h0l);
        float bj[4] = {bias.x, bias.y, bias.z, bias.w};
        #pragma unroll
        for (int n = 0; n < 4; ++n) {
            const int bt = b_panel * 8 + wc * 4 + n;
            unsigned mk[4];
            #pragma unroll
            for (int j = 0; j < 4; ++j) {
                float i1 = __fmul_rn((float)acc[m][n][j], 3.0517578125e-05f) + bj[j];
                float arg = fmaf(-0.1f, __builtin_amdgcn_rcpf(i1), 1.0f);
                float pf = ceilf(__log2f(arg) * -6.578813478960192f);
                int p = (int)pf;
                p = p < 1 ? 1 : (p > 21 ? 21 : p);
                unsigned mask = lutm[p];
                mk[j] = (i1 >= 0.113843485f) ? mask : 0u;
                spikes += __popc(mk[j]);
            }
            const size_t rec = ((size_t)bt * 32 + kt64) * 64 + k2lane;
            *reinterpret_cast<uint2*>(M16 + rec * 16 + g * 4) =
                make_uint2((mk[0] & 0xffffu) | (mk[1] << 16),
                           (mk[2] & 0xffffu) | (mk[3] << 16));
            *reinterpret_cast<unsigned int*>(M4 + rec * 16 + g * 4) =
                (mk[0] >> 16) | ((mk[1] >> 16) << 8) | ((mk[2] >> 16) << 16) | ((mk[3] >> 16) << 24);
        }
    }
    #pragma unroll
    for (int off = 32; off > 0; off >>= 1)
        spikes += __shfl_down(spikes, off);
    if (lane == 0)
        atomicAdd(spike_count, (unsigned int)spikes);
}

// ---------------- K2: layer 2 via i8 MFMA K=64, mask-prefetch double-buffer ----------
// Streaming mask loads (100 MB HBM, ~900cyc) now issue one kt ahead, overlapping
// the previous kt's A-expand + 40 MFMAs.
__global__ __launch_bounds__(256, 2) void k_layer2_i8(
    const unsigned short* __restrict__ M16,
    const unsigned char* __restrict__ M4,
    const signed char* __restrict__ W2q,
    const float* __restrict__ b2,
    float* __restrict__ out)
{
    __shared__ __align__(16) float smem[5700];   // 16b x 16c (pad 17) x 21t
    const int tid  = threadIdx.x;
    const int tg   = tid >> 6;        // wave = t-group: t in [tg*5, tg*5+5)
    const int lane = tid & 63;
    const int l15  = lane & 15;
    const int g    = lane >> 4;
    const int b0   = blockIdx.x * 16;
    const int t0   = tg * 5;

    i32x4 acc[8][5];
    #pragma unroll
    for (int n = 0; n < 8; ++n)
        #pragma unroll
        for (int t = 0; t < 5; ++t)
            acc[n][t] = (i32x4){0, 0, 0, 0};

    const unsigned short* m16p = M16 + (size_t)blockIdx.x * 32768 + lane * 16;
    const unsigned char*  m4p  = M4  + (size_t)blockIdx.x * 32768 + lane * 16;
    const signed char*    fbase = W2q + (size_t)lane * 16;

    uint4 wa[2], wb[2], w4v[2];
    wa[0] = *reinterpret_cast<const uint4*>(m16p);
    wb[0] = *reinterpret_cast<const uint4*>(m16p + 8);
    w4v[0] = (tg == 3) ? *reinterpret_cast<const uint4*>(m4p)
                       : make_uint4(0u, 0u, 0u, 0u);

    #pragma unroll 2
    for (int kt = 0; kt < 32; ++kt) {
        const int cur = kt & 1, nxt = cur ^ 1;
        if (kt < 31) {
            const unsigned short* mpn = m16p + (size_t)(kt + 1) * 1024;
            wa[nxt] = *reinterpret_cast<const uint4*>(mpn);
            wb[nxt] = *reinterpret_cast<const uint4*>(mpn + 8);
            w4v[nxt] = (tg == 3) ? *reinterpret_cast<const uint4*>(m4p + (size_t)(kt + 1) * 1024)
                                 : make_uint4(0u, 0u, 0u, 0u);
        }

        union { i32x4 v; unsigned u[4]; } A[5];
        #pragma unroll
        for (int tl = 0; tl < 5; ++tl) {
            const int t = t0 + tl;
            if (t < 16) {
                A[tl].u[0] = ((wa[cur].x >> t) & 0x10001u) | (((wa[cur].y >> t) & 0x10001u) << 8);
                A[tl].u[1] = ((wa[cur].z >> t) & 0x10001u) | (((wa[cur].w >> t) & 0x10001u) << 8);
                A[tl].u[2] = ((wb[cur].x >> t) & 0x10001u) | (((wb[cur].y >> t) & 0x10001u) << 8);
                A[tl].u[3] = ((wb[cur].z >> t) & 0x10001u) | (((wb[cur].w >> t) & 0x10001u) << 8);
            } else {
                const int tt = t - 16;
                A[tl].u[0] = __builtin_amdgcn_perm(0u, (w4v[cur].x >> tt) & 0x01010101u, 0x03010200u);
                A[tl].u[1] = __builtin_amdgcn_perm(0u, (w4v[cur].y >> tt) & 0x01010101u, 0x03010200u);
                A[tl].u[2] = __builtin_amdgcn_perm(0u, (w4v[cur].z >> tt) & 0x01010101u, 0x03010200u);
                A[tl].u[3] = __builtin_amdgcn_perm(0u, (w4v[cur].w >> tt) & 0x01010101u, 0x03010200u);
            }
        }

        const signed char* fk = fbase + (size_t)kt * 8192;
        i32x4 Bv[8];
        #pragma unroll
        for (int nt = 0; nt < 8; ++nt)
            Bv[nt] = *reinterpret_cast<const i32x4*>(fk + nt * 1024);
        #pragma unroll
        for (int tl = 0; tl < 5; ++tl)
            #pragma unroll
            for (int nt = 0; nt < 8; ++nt)
                acc[nt][tl] = __builtin_amdgcn_mfma_i32_16x16x64_i8(
                    A[tl].v, Bv[nt], acc[nt][tl], 0, 0, 0);
    }

    // epilogue: 8 chunks of 16 cols; transpose through LDS, then LIF per (b,c)
    #pragma unroll
    for (int q = 0; q < 8; ++q) {
        __syncthreads();
        #pragma unroll
        for (int tl = 0; tl < 5; ++tl)
            #pragma unroll
            for (int j = 0; j < 4; ++j)
                smem[((g * 4 + j) * 17 + l15) * 21 + (t0 + tl)] = (float)acc[q][tl][j];
        __syncthreads();
        {
            const int bl  = tid >> 4;     // 0..15
            const int c16 = tid & 15;
            const int c   = q * 16 + c16;
            const float bias = b2[c];
            float u2 = 0.0f; int cnt = 0;
            #pragma unroll
            for (int t = 0; t < T_STEPS; ++t) {
                float X = __fadd_rn(__fmul_rn(smem[(bl * 17 + c16) * 21 + t], 0.0009765625f), bias);
                u2 = __fadd_rn(__fmul_rn(0.9f, u2), X);
                if (u2 >= 1.0f) { cnt++; u2 = 0.0f; }
            }
            out[(size_t)(b0 + bl) * C_SZ + c] = (float)cnt / 20.0f;
        }
    }
}

// ---------------- K3: mean_spikes = total / (B * T) ----------------
__global__ void k_finalize(const unsigned int* __restrict__ spike_count, float* __restrict__ out) {
    out[(size_t)B_SZ * C_SZ] = (float)(*spike_count) / (float)((size_t)B_SZ * T_STEPS);
}

extern "C" void kernel_launch(void* const* d_in, const int* in_sizes, int n_in,
                              void* d_out, int out_size, void* d_ws, size_t ws_size,
                              hipStream_t stream) {
    const float* x  = (const float*)d_in[0];
    const float* W1 = (const float*)d_in[1];
    const float* b1 = (const float*)d_in[2];
    const float* W2 = (const float*)d_in[3];
    const float* b2 = (const float*)d_in[4];
    float* out = (float*)d_out;

    char* ws = (char*)d_ws;
    const size_t m16_b  = (size_t)B_SZ * H_SZ * 2;   // 67.1 MB
    const size_t m4_b   = (size_t)B_SZ * H_SZ;       // 33.6 MB
    const size_t xfi_b  = (size_t)B_SZ * D_SZ;       // 16.8 MB
    const size_t w1fi_b = (size_t)H_SZ * D_SZ;       //  2.1 MB
    const size_t w2q_b  = (size_t)C_SZ * H_SZ;       //  0.26 MB

    size_t off = 0;
    unsigned short* M16  = (unsigned short*)(ws + off); off += m16_b;
    unsigned char*  M4   = (unsigned char*)(ws + off);  off += m4_b;
    signed char*    xfi  = (signed char*)(ws + off);    off += xfi_b;
    signed char*    w1fi = (signed char*)(ws + off);    off += w1fi_b;
    signed char*    w2q  = (signed char*)(ws + off);    off += w2q_b;
    unsigned int* counter = (unsigned int*)(ws + off);  off += 256;

    hipMemsetAsync(counter, 0, sizeof(unsigned int), stream);

    k_w1fragi8<<<512, 256, 0, stream>>>(W1, w1fi);   // 131072 threads EXACT
    k_w2fragi8<<<64, 256, 0, stream>>>(W2, w2q);     // 16384 threads EXACT
    k_xfragi8<<<4096, 256, 0, stream>>>(x, xfi);     // 1048576 threads EXACT

    k_gemm1_i8<<<2048, 256, 0, stream>>>(xfi, w1fi, b1, M16, M4, counter);

    k_layer2_i8<<<B_SZ / 16, 256, 0, stream>>>(M16, M4, w2q, b2, out);

    k_finalize<<<1, 1, 0, stream>>>(counter, out);
}

// Round 17
// 248.520 us; speedup vs baseline: 1.0037x; 1.0037x over previous
//
#include <hip/hip_runtime.h>

#define B_SZ 16384
#define D_SZ 1024
#define H_SZ 2048
#define C_SZ 128
#define T_STEPS 20

typedef __attribute__((ext_vector_type(4))) float f32x4;
typedef __attribute__((ext_vector_type(4))) int   i32x4;

__device__ __forceinline__ signed char to_i8(float f, float s) {
    float v = rintf(s * f);
    v = v > 127.0f ? 127.0f : (v < -127.0f ? -127.0f : v);
    return (signed char)(int)v;
}

__device__ __forceinline__ void gl_lds16(const void* g, void* l) {
    __builtin_amdgcn_global_load_lds(
        (const __attribute__((address_space(1))) unsigned int*)g,
        (__attribute__((address_space(3))) unsigned int*)l, 16, 0, 0);
}

// ---------------- W1 -> i8 frags: [p(16)][kt(16)][wr(2)][m(4)][lane(64)][16B] --------
__global__ void k_w1fragi8(const float* __restrict__ W1, signed char* __restrict__ w1f) {
    int idx = blockIdx.x * blockDim.x + threadIdx.x;   // 0..131071
    int lane = idx & 63;
    int m    = (idx >> 6) & 3;
    int wr   = (idx >> 8) & 1;
    int kt   = (idx >> 9) & 15;
    int p    = idx >> 13;
    int h = p * 128 + wr * 64 + m * 16 + (lane & 15);
    int k = kt * 64 + (lane >> 4) * 16;
    const float* src = W1 + (size_t)h * D_SZ + k;
    union { signed char b[16]; uint4 u; } q;
    #pragma unroll
    for (int q4 = 0; q4 < 4; ++q4) {
        float4 v = *reinterpret_cast<const float4*>(src + q4 * 4);
        q.b[q4 * 4 + 0] = to_i8(v.x, 1024.0f);
        q.b[q4 * 4 + 1] = to_i8(v.y, 1024.0f);
        q.b[q4 * 4 + 2] = to_i8(v.z, 1024.0f);
        q.b[q4 * 4 + 3] = to_i8(v.w, 1024.0f);
    }
    size_t off = (size_t)p * 131072 + (size_t)kt * 8192 + wr * 4096 + m * 1024 + lane * 16;
    *reinterpret_cast<uint4*>(w1f + off) = q.u;
}

// ---------------- x -> i8 frags: [bp(128)][kt(16)][wc(2)][n(4)][lane(64)][16B] -------
__global__ void k_xfragi8(const float* __restrict__ x, signed char* __restrict__ xf) {
    int idx = blockIdx.x * blockDim.x + threadIdx.x;   // 0..1048575
    int lane = idx & 63;
    int n    = (idx >> 6) & 3;
    int wc   = (idx >> 8) & 1;
    int kt   = (idx >> 9) & 15;
    int bp   = idx >> 13;
    int b = bp * 128 + wc * 64 + n * 16 + (lane & 15);
    int k = kt * 64 + (lane >> 4) * 16;
    const float* src = x + (size_t)b * D_SZ + k;
    union { signed char b[16]; uint4 u; } q;
    #pragma unroll
    for (int q4 = 0; q4 < 4; ++q4) {
        float4 v = *reinterpret_cast<const float4*>(src + q4 * 4);
        q.b[q4 * 4 + 0] = to_i8(v.x, 32.0f);
        q.b[q4 * 4 + 1] = to_i8(v.y, 32.0f);
        q.b[q4 * 4 + 2] = to_i8(v.z, 32.0f);
        q.b[q4 * 4 + 3] = to_i8(v.w, 32.0f);
    }
    size_t off = (size_t)bp * 131072 + (size_t)kt * 8192 + wc * 4096 + n * 1024 + lane * 16;
    *reinterpret_cast<uint4*>(xf + off) = q.u;
}

// ---------------- W2 -> i8 frags: [kt64(32)][nt(8)][lane(64)][16B], k-perm baked -----
__global__ void k_w2fragi8(const float* __restrict__ W2, signed char* __restrict__ w2q) {
    const int perm4[4] = {0, 2, 1, 3};
    int idx = blockIdx.x * blockDim.x + threadIdx.x;   // 0..16383
    int lane = idx & 63;
    int nt   = (idx >> 6) & 7;
    int kt   = idx >> 9;                               // 0..31
    int c = nt * 16 + (lane & 15);
    int hbase = kt * 64 + (lane >> 4) * 16;
    const float* src = W2 + (size_t)c * H_SZ + hbase;
    float f[16];
    #pragma unroll
    for (int q4 = 0; q4 < 4; ++q4) {
        float4 v = *reinterpret_cast<const float4*>(src + q4 * 4);
        f[q4 * 4 + 0] = v.x; f[q4 * 4 + 1] = v.y; f[q4 * 4 + 2] = v.z; f[q4 * 4 + 3] = v.w;
    }
    union { signed char b[16]; uint4 u; } q;
    #pragma unroll
    for (int j = 0; j < 16; ++j) {
        int k = (j & ~3) + perm4[j & 3];
        q.b[j] = to_i8(f[k], 1024.0f);
    }
    *reinterpret_cast<uint4*>(w2q + (size_t)idx * 16) = q.u;
}

// ---------------- K1: LDS-staged i8 GEMM (m97 structure) + closed-form LIF -----------
// 32KB LDS double-buffer; per kt: stage next 16KB via global_load_lds (fire-and-
// forget, drained by next barrier) -> 8 ds_read_b128 -> 16 MFMA. One barrier/iter.
// M16 layout: [bt][kt64][half(2)][lane(64)][8u16]  (half = g>>1); M4: [bt][kt64][lane][16B].
__global__ __launch_bounds__(256, 2) void k_gemm1_i8(
    const signed char* __restrict__ xf,
    const signed char* __restrict__ w1f,
    const float* __restrict__ b1,
    unsigned short* __restrict__ M16,
    unsigned char* __restrict__ M4,
    unsigned int* __restrict__ spike_count)
{
    __shared__ unsigned lutm[22];
    __shared__ __align__(16) char sbuf[2][16384];   // [buf][A 8KB | B 8KB]
    const int tid  = threadIdx.x;
    if (tid < 22) {
        unsigned m = 0;
        if (tid >= 1 && tid <= 20)
            for (int t = tid - 1; t < T_STEPS; t += tid) m |= 1u << t;
        lutm[tid] = m;
    }

    const int wv   = tid >> 6;
    const int lane = tid & 63;
    const int l15  = lane & 15;
    const int g    = lane >> 4;
    const int wr   = wv >> 1;
    const int wc   = wv & 1;

    const int wg    = blockIdx.x;
    const int xcd   = wg & 7;
    const int local = wg >> 3;
    const int sc    = local >> 4;
    const int sl    = local & 15;
    const int b_panel = xcd * 16 + (sc >> 2) * 4 + (sl >> 2);
    const int h_idx   = (sc & 3) * 4 + (sl & 3);

    const signed char* Asrc = w1f + (size_t)h_idx * 131072;
    const signed char* Bsrc = xf + (size_t)b_panel * 131072;

    // prologue: stage kt=0 into buf 0
    #pragma unroll
    for (int c = 0; c < 4; ++c) {
        int o = c * 4096 + wv * 1024;
        const signed char* s = (o < 8192) ? (Asrc + o + lane * 16)
                                          : (Bsrc + (o - 8192) + lane * 16);
        gl_lds16(s, sbuf[0] + o);
    }

    i32x4 acc[4][4];
    #pragma unroll
    for (int i = 0; i < 4; ++i)
        #pragma unroll
        for (int j = 0; j < 4; ++j)
            acc[i][j] = (i32x4){0, 0, 0, 0};

    for (int kt = 0; kt < 16; ++kt) {
        __syncthreads();           // drains staging of buf[kt&1] (vmcnt before barrier)
        if (kt < 15) {
            #pragma unroll
            for (int c = 0; c < 4; ++c) {
                int o = c * 4096 + wv * 1024;
                const signed char* s = (o < 8192)
                    ? (Asrc + (size_t)(kt + 1) * 8192 + o + lane * 16)
                    : (Bsrc + (size_t)(kt + 1) * 8192 + (o - 8192) + lane * 16);
                gl_lds16(s, sbuf[(kt + 1) & 1] + o);
            }
        }
        const char* base = sbuf[kt & 1];
        i32x4 A[4], Bv[4];
        #pragma unroll
        for (int m = 0; m < 4; ++m)
            A[m] = *reinterpret_cast<const i32x4*>(base + wr * 4096 + m * 1024 + lane * 16);
        #pragma unroll
        for (int n = 0; n < 4; ++n)
            Bv[n] = *reinterpret_cast<const i32x4*>(base + 8192 + wc * 4096 + n * 1024 + lane * 16);
        #pragma unroll
        for (int m = 0; m < 4; ++m)
            #pragma unroll
            for (int n = 0; n < 4; ++n)
                acc[m][n] = __builtin_amdgcn_mfma_i32_16x16x64_i8(
                    A[m], Bv[n], acc[m][n], 0, 0, 0);
    }

    int spikes = 0;
    #pragma unroll
    for (int m = 0; m < 4; ++m) {
        const int h0l = h_idx * 128 + wr * 64 + m * 16 + g * 4;
        const int kt64 = h_idx * 2 + wr;
        const int k2lane = m * 16 + l15;
        float4 bias = *reinterpret_cast<const float4*>(b1 + h0l);
        float bj[4] = {bias.x, bias.y, bias.z, bias.w};
        #pragma unroll
        for (int n = 0; n < 4; ++n) {
            const int bt = b_panel * 8 + wc * 4 + n;
            unsigned mk[4];
            #pragma unroll
            for (int j = 0; j < 4; ++j) {
                float i1 = __fmul_rn((float)acc[m][n][j], 3.0517578125e-05f) + bj[j];
                float arg = fmaf(-0.1f, __builtin_amdgcn_rcpf(i1), 1.0f);
                float pf = ceilf(__log2f(arg) * -6.578813478960192f);
                int p = (int)pf;
                p = p < 1 ? 1 : (p > 21 ? 21 : p);
                unsigned mask = lutm[p];
                mk[j] = (i1 >= 0.113843485f) ? mask : 0u;
                spikes += __popc(mk[j]);
            }
            // M16: [bt][kt64][half][lane][8u16]; half = g>>1, 8B sub-slot = g&1
            const size_t m16byte = (((size_t)bt * 32 + kt64) * 2 + (g >> 1)) * 1024
                                 + (size_t)k2lane * 16 + (g & 1) * 8;
            *reinterpret_cast<uint2*>((char*)M16 + m16byte) =
                make_uint2((mk[0] & 0xffffu) | (mk[1] << 16),
                           (mk[2] & 0xffffu) | (mk[3] << 16));
            const size_t m4byte = ((size_t)bt * 32 + kt64) * 1024 + (size_t)k2lane * 16 + g * 4;
            *reinterpret_cast<unsigned int*>((char*)M4 + m4byte) =
                (mk[0] >> 16) | ((mk[1] >> 16) << 8) | ((mk[2] >> 16) << 16) | ((mk[3] >> 16) << 24);
        }
    }
    #pragma unroll
    for (int off = 32; off > 0; off >>= 1)
        spikes += __shfl_down(spikes, off);
    if (lane == 0)
        atomicAdd(spike_count, (unsigned int)spikes);
}

// ---------------- K2: layer 2 i8 K=64, LDS-staged masks + W2 (m97 structure) ---------
// Per kt stage {w2 8KB, m16 2KB, m4 1KB} into 2x11KB double-buffer (de-dupes the 4x
// per-wave redundant loads); barrier; ds_read + expand + 40 MFMA. Epilogue unions LDS.
__global__ __launch_bounds__(256, 2) void k_layer2_i8(
    const unsigned short* __restrict__ M16,
    const unsigned char* __restrict__ M4,
    const signed char* __restrict__ W2q,
    const float* __restrict__ b2,
    float* __restrict__ out)
{
    __shared__ __align__(16) char smem[23040];   // union{ stage 2x11264B, 5700 floats }
    float* sm_f32 = (float*)smem;

    const int tid  = threadIdx.x;
    const int wv   = tid >> 6;
    const int tg   = wv;              // wave = t-group: t in [tg*5, tg*5+5)
    const int lane = tid & 63;
    const int l15  = lane & 15;
    const int g    = lane >> 4;
    const int b0   = blockIdx.x * 16;
    const int t0   = tg * 5;

    const size_t m16blk = (size_t)blockIdx.x * 65536;   // bytes
    const size_t m4blk  = (size_t)blockIdx.x * 32768;   // bytes

    i32x4 acc[8][5];
    #pragma unroll
    for (int n = 0; n < 8; ++n)
        #pragma unroll
        for (int t = 0; t < 5; ++t)
            acc[n][t] = (i32x4){0, 0, 0, 0};

    // prologue: stage kt=0 into buf 0. 11 chunks of 1KB: [0..7]=w2, [8,9]=m16, [10]=m4
    for (int c = wv; c < 11; c += 4) {
        const char* s;
        if (c < 8)       s = (const char*)W2q + c * 1024;
        else if (c < 10) s = (const char*)M16 + m16blk + (c - 8) * 1024;
        else             s = (const char*)M4 + m4blk;
        gl_lds16(s + lane * 16, smem + c * 1024);
    }

    for (int kt = 0; kt < 32; ++kt) {
        __syncthreads();
        const int cb = (kt & 1) * 11264;
        if (kt < 31) {
            const int nb = ((kt + 1) & 1) * 11264;
            for (int c = wv; c < 11; c += 4) {
                const char* s;
                if (c < 8)       s = (const char*)W2q + (size_t)(kt + 1) * 8192 + c * 1024;
                else if (c < 10) s = (const char*)M16 + m16blk + (size_t)(kt + 1) * 2048 + (c - 8) * 1024;
                else             s = (const char*)M4 + m4blk + (size_t)(kt + 1) * 1024;
                gl_lds16(s + lane * 16, smem + nb + c * 1024);
            }
        }

        uint4 wa = *reinterpret_cast<const uint4*>(smem + cb + 8192 + lane * 16);
        uint4 wb = *reinterpret_cast<const uint4*>(smem + cb + 9216 + lane * 16);
        uint4 w4 = make_uint4(0u, 0u, 0u, 0u);
        if (tg == 3)
            w4 = *reinterpret_cast<const uint4*>(smem + cb + 10240 + lane * 16);

        union { i32x4 v; unsigned u[4]; } A[5];
        #pragma unroll
        for (int tl = 0; tl < 5; ++tl) {
            const int t = t0 + tl;
            if (t < 16) {
                A[tl].u[0] = ((wa.x >> t) & 0x10001u) | (((wa.y >> t) & 0x10001u) << 8);
                A[tl].u[1] = ((wa.z >> t) & 0x10001u) | (((wa.w >> t) & 0x10001u) << 8);
                A[tl].u[2] = ((wb.x >> t) & 0x10001u) | (((wb.y >> t) & 0x10001u) << 8);
                A[tl].u[3] = ((wb.z >> t) & 0x10001u) | (((wb.w >> t) & 0x10001u) << 8);
            } else {
                const int tt = t - 16;
                A[tl].u[0] = __builtin_amdgcn_perm(0u, (w4.x >> tt) & 0x01010101u, 0x03010200u);
                A[tl].u[1] = __builtin_amdgcn_perm(0u, (w4.y >> tt) & 0x01010101u, 0x03010200u);
                A[tl].u[2] = __builtin_amdgcn_perm(0u, (w4.z >> tt) & 0x01010101u, 0x03010200u);
                A[tl].u[3] = __builtin_amdgcn_perm(0u, (w4.w >> tt) & 0x01010101u, 0x03010200u);
            }
        }

        i32x4 Bv[8];
        #pragma unroll
        for (int nt = 0; nt < 8; ++nt)
            Bv[nt] = *reinterpret_cast<const i32x4*>(smem + cb + nt * 1024 + lane * 16);
        #pragma unroll
        for (int tl = 0; tl < 5; ++tl)
            #pragma unroll
            for (int nt = 0; nt < 8; ++nt)
                acc[nt][tl] = __builtin_amdgcn_mfma_i32_16x16x64_i8(
                    A[tl].v, Bv[nt], acc[nt][tl], 0, 0, 0);
    }

    // epilogue: 8 chunks of 16 cols; transpose through LDS, then LIF per (b,c)
    #pragma unroll
    for (int q = 0; q < 8; ++q) {
        __syncthreads();
        #pragma unroll
        for (int tl = 0; tl < 5; ++tl)
            #pragma unroll
            for (int j = 0; j < 4; ++j)
                sm_f32[((g * 4 + j) * 17 + l15) * 21 + (t0 + tl)] = (float)acc[q][tl][j];
        __syncthreads();
        {
            const int bl  = tid >> 4;     // 0..15
            const int c16 = tid & 15;
            const int c   = q * 16 + c16;
            const float bias = b2[c];
            float u2 = 0.0f; int cnt = 0;
            #pragma unroll
            for (int t = 0; t < T_STEPS; ++t) {
                float X = __fadd_rn(__fmul_rn(sm_f32[(bl * 17 + c16) * 21 + t], 0.0009765625f), bias);
                u2 = __fadd_rn(__fmul_rn(0.9f, u2), X);
                if (u2 >= 1.0f) { cnt++; u2 = 0.0f; }
            }
            out[(size_t)(b0 + bl) * C_SZ + c] = (float)cnt / 20.0f;
        }
    }
}

// ---------------- K3: mean_spikes = total / (B * T) ----------------
__global__ void k_finalize(const unsigned int* __restrict__ spike_count, float* __restrict__ out) {
    out[(size_t)B_SZ * C_SZ] = (float)(*spike_count) / (float)((size_t)B_SZ * T_STEPS);
}

extern "C" void kernel_launch(void* const* d_in, const int* in_sizes, int n_in,
                              void* d_out, int out_size, void* d_ws, size_t ws_size,
                              hipStream_t stream) {
    const float* x  = (const float*)d_in[0];
    const float* W1 = (const float*)d_in[1];
    const float* b1 = (const float*)d_in[2];
    const float* W2 = (const float*)d_in[3];
    const float* b2 = (const float*)d_in[4];
    float* out = (float*)d_out;

    char* ws = (char*)d_ws;
    const size_t m16_b  = (size_t)B_SZ * H_SZ * 2;   // 67.1 MB
    const size_t m4_b   = (size_t)B_SZ * H_SZ;       // 33.6 MB
    const size_t xfi_b  = (size_t)B_SZ * D_SZ;       // 16.8 MB
    const size_t w1fi_b = (size_t)H_SZ * D_SZ;       //  2.1 MB
    const size_t w2q_b  = (size_t)C_SZ * H_SZ;       //  0.26 MB

    size_t off = 0;
    unsigned short* M16  = (unsigned short*)(ws + off); off += m16_b;
    unsigned char*  M4   = (unsigned char*)(ws + off);  off += m4_b;
    signed char*    xfi  = (signed char*)(ws + off);    off += xfi_b;
    signed char*    w1fi = (signed char*)(ws + off);    off += w1fi_b;
    signed char*    w2q  = (signed char*)(ws + off);    off += w2q_b;
    unsigned int* counter = (unsigned int*)(ws + off);  off += 256;

    hipMemsetAsync(counter, 0, sizeof(unsigned int), stream);

    k_w1fragi8<<<512, 256, 0, stream>>>(W1, w1fi);   // 131072 threads EXACT
    k_w2fragi8<<<64, 256, 0, stream>>>(W2, w2q);     // 16384 threads EXACT
    k_xfragi8<<<4096, 256, 0, stream>>>(x, xfi);     // 1048576 threads EXACT

    k_gemm1_i8<<<2048, 256, 0, stream>>>(xfi, w1fi, b1, M16, M4, counter);

    k_layer2_i8<<<B_SZ / 16, 256, 0, stream>>>(M16, M4, w2q, b2, out);

    k_finalize<<<1, 1, 0, stream>>>(counter, out);
}

// Round 18
// 194.956 us; speedup vs baseline: 1.2795x; 1.2747x over previous
//
#include <hip/hip_runtime.h>

#define B_SZ 16384
#define D_SZ 1024
#define H_SZ 2048
#define C_SZ 128
#define T_STEPS 20

typedef __attribute__((ext_vector_type(4))) float f32x4;
typedef __attribute__((ext_vector_type(4))) int   i32x4;

__device__ __forceinline__ signed char to_i8(float f, float s) {
    float v = rintf(s * f);
    v = v > 127.0f ? 127.0f : (v < -127.0f ? -127.0f : v);
    return (signed char)(int)v;
}

__device__ __forceinline__ void gl_lds16(const void* g, void* l) {
    __builtin_amdgcn_global_load_lds(
        (const __attribute__((address_space(1))) unsigned int*)g,
        (__attribute__((address_space(3))) unsigned int*)l, 16, 0, 0);
}

// ---------------- W1 -> i8 frags: [p(16)][kt(16)][wr(2)][m(4)][lane(64)][16B] --------
__global__ void k_w1fragi8(const float* __restrict__ W1, signed char* __restrict__ w1f) {
    int idx = blockIdx.x * blockDim.x + threadIdx.x;   // 0..131071
    int lane = idx & 63;
    int m    = (idx >> 6) & 3;
    int wr   = (idx >> 8) & 1;
    int kt   = (idx >> 9) & 15;
    int p    = idx >> 13;
    int h = p * 128 + wr * 64 + m * 16 + (lane & 15);
    int k = kt * 64 + (lane >> 4) * 16;
    const float* src = W1 + (size_t)h * D_SZ + k;
    union { signed char b[16]; uint4 u; } q;
    #pragma unroll
    for (int q4 = 0; q4 < 4; ++q4) {
        float4 v = *reinterpret_cast<const float4*>(src + q4 * 4);
        q.b[q4 * 4 + 0] = to_i8(v.x, 1024.0f);
        q.b[q4 * 4 + 1] = to_i8(v.y, 1024.0f);
        q.b[q4 * 4 + 2] = to_i8(v.z, 1024.0f);
        q.b[q4 * 4 + 3] = to_i8(v.w, 1024.0f);
    }
    size_t off = (size_t)p * 131072 + (size_t)kt * 8192 + wr * 4096 + m * 1024 + lane * 16;
    *reinterpret_cast<uint4*>(w1f + off) = q.u;
}

// ---------------- x -> i8 frags: [bp(128)][kt(16)][wc(2)][n(4)][lane(64)][16B] -------
__global__ void k_xfragi8(const float* __restrict__ x, signed char* __restrict__ xf) {
    int idx = blockIdx.x * blockDim.x + threadIdx.x;   // 0..1048575
    int lane = idx & 63;
    int n    = (idx >> 6) & 3;
    int wc   = (idx >> 8) & 1;
    int kt   = (idx >> 9) & 15;
    int bp   = idx >> 13;
    int b = bp * 128 + wc * 64 + n * 16 + (lane & 15);
    int k = kt * 64 + (lane >> 4) * 16;
    const float* src = x + (size_t)b * D_SZ + k;
    union { signed char b[16]; uint4 u; } q;
    #pragma unroll
    for (int q4 = 0; q4 < 4; ++q4) {
        float4 v = *reinterpret_cast<const float4*>(src + q4 * 4);
        q.b[q4 * 4 + 0] = to_i8(v.x, 32.0f);
        q.b[q4 * 4 + 1] = to_i8(v.y, 32.0f);
        q.b[q4 * 4 + 2] = to_i8(v.z, 32.0f);
        q.b[q4 * 4 + 3] = to_i8(v.w, 32.0f);
    }
    size_t off = (size_t)bp * 131072 + (size_t)kt * 8192 + wc * 4096 + n * 1024 + lane * 16;
    *reinterpret_cast<uint4*>(xf + off) = q.u;
}

// ---------------- W2 -> i8 frags: [kt64(32)][nt(8)][lane(64)][16B], k-perm baked -----
__global__ void k_w2fragi8(const float* __restrict__ W2, signed char* __restrict__ w2q) {
    const int perm4[4] = {0, 2, 1, 3};
    int idx = blockIdx.x * blockDim.x + threadIdx.x;   // 0..16383
    int lane = idx & 63;
    int nt   = (idx >> 6) & 7;
    int kt   = idx >> 9;                               // 0..31
    int c = nt * 16 + (lane & 15);
    int hbase = kt * 64 + (lane >> 4) * 16;
    const float* src = W2 + (size_t)c * H_SZ + hbase;
    float f[16];
    #pragma unroll
    for (int q4 = 0; q4 < 4; ++q4) {
        float4 v = *reinterpret_cast<const float4*>(src + q4 * 4);
        f[q4 * 4 + 0] = v.x; f[q4 * 4 + 1] = v.y; f[q4 * 4 + 2] = v.z; f[q4 * 4 + 3] = v.w;
    }
    union { signed char b[16]; uint4 u; } q;
    #pragma unroll
    for (int j = 0; j < 16; ++j) {
        int k = (j & ~3) + perm4[j & 3];
        q.b[j] = to_i8(f[k], 1024.0f);
    }
    *reinterpret_cast<uint4*>(w2q + (size_t)idx * 16) = q.u;
}

// ---------------- K1: LDS-staged i8 GEMM + closed-form LIF, 1-byte p-code masks ------
// Spike mask = f(period p) -> store p (1B) instead of 3B mask: write stream 100->33MB
// (round 12->13 calibration: ~1.6 TB/s effective writes => ~40us saved).
// M5 layout: [bt(1024)][kt64(32)][rec(64)][16B]; rec = m*16+l15, byte = g*4+j.
__global__ __launch_bounds__(256, 2) void k_gemm1_i8(
    const signed char* __restrict__ xf,
    const signed char* __restrict__ w1f,
    const float* __restrict__ b1,
    unsigned char* __restrict__ M5,
    unsigned int* __restrict__ spike_count)
{
    __shared__ unsigned lutm[22];
    __shared__ int sred[4];
    __shared__ __align__(16) char sbuf[2][16384];   // [buf][A 8KB | B 8KB]
    const int tid  = threadIdx.x;
    if (tid < 22) {
        unsigned m = 0;
        if (tid >= 1 && tid <= 20)
            for (int t = tid - 1; t < T_STEPS; t += tid) m |= 1u << t;
        lutm[tid] = m;
    }

    const int wv   = tid >> 6;
    const int lane = tid & 63;
    const int l15  = lane & 15;
    const int g    = lane >> 4;
    const int wr   = wv >> 1;
    const int wc   = wv & 1;

    const int wg    = blockIdx.x;
    const int xcd   = wg & 7;
    const int local = wg >> 3;
    const int sc    = local >> 4;
    const int sl    = local & 15;
    const int b_panel = xcd * 16 + (sc >> 2) * 4 + (sl >> 2);
    const int h_idx   = (sc & 3) * 4 + (sl & 3);

    const signed char* Asrc = w1f + (size_t)h_idx * 131072;
    const signed char* Bsrc = xf + (size_t)b_panel * 131072;

    #pragma unroll
    for (int c = 0; c < 4; ++c) {
        int o = c * 4096 + wv * 1024;
        const signed char* s = (o < 8192) ? (Asrc + o + lane * 16)
                                          : (Bsrc + (o - 8192) + lane * 16);
        gl_lds16(s, sbuf[0] + o);
    }

    i32x4 acc[4][4];
    #pragma unroll
    for (int i = 0; i < 4; ++i)
        #pragma unroll
        for (int j = 0; j < 4; ++j)
            acc[i][j] = (i32x4){0, 0, 0, 0};

    for (int kt = 0; kt < 16; ++kt) {
        __syncthreads();
        if (kt < 15) {
            #pragma unroll
            for (int c = 0; c < 4; ++c) {
                int o = c * 4096 + wv * 1024;
                const signed char* s = (o < 8192)
                    ? (Asrc + (size_t)(kt + 1) * 8192 + o + lane * 16)
                    : (Bsrc + (size_t)(kt + 1) * 8192 + (o - 8192) + lane * 16);
                gl_lds16(s, sbuf[(kt + 1) & 1] + o);
            }
        }
        const char* base = sbuf[kt & 1];
        i32x4 A[4], Bv[4];
        #pragma unroll
        for (int m = 0; m < 4; ++m)
            A[m] = *reinterpret_cast<const i32x4*>(base + wr * 4096 + m * 1024 + lane * 16);
        #pragma unroll
        for (int n = 0; n < 4; ++n)
            Bv[n] = *reinterpret_cast<const i32x4*>(base + 8192 + wc * 4096 + n * 1024 + lane * 16);
        #pragma unroll
        for (int m = 0; m < 4; ++m)
            #pragma unroll
            for (int n = 0; n < 4; ++n)
                acc[m][n] = __builtin_amdgcn_mfma_i32_16x16x64_i8(
                    A[m], Bv[n], acc[m][n], 0, 0, 0);
    }

    int spikes = 0;
    #pragma unroll
    for (int m = 0; m < 4; ++m) {
        const int h0l = h_idx * 128 + wr * 64 + m * 16 + g * 4;
        const int kt64 = h_idx * 2 + wr;
        const int k2lane = m * 16 + l15;
        float4 bias = *reinterpret_cast<const float4*>(b1 + h0l);
        float bj[4] = {bias.x, bias.y, bias.z, bias.w};
        #pragma unroll
        for (int n = 0; n < 4; ++n) {
            const int bt = b_panel * 8 + wc * 4 + n;
            unsigned pcode = 0;
            #pragma unroll
            for (int j = 0; j < 4; ++j) {
                float i1 = __fmul_rn((float)acc[m][n][j], 3.0517578125e-05f) + bj[j];
                float arg = fmaf(-0.1f, __builtin_amdgcn_rcpf(i1), 1.0f);
                float pf = ceilf(__log2f(arg) * -6.578813478960192f);
                int p = (int)pf;
                p = p < 1 ? 1 : (p > 21 ? 21 : p);
                int pe = (i1 >= 0.113843485f) ? p : 0;
                spikes += __popc(lutm[pe]);
                pcode |= (unsigned)pe << (8 * j);
            }
            const size_t rec = ((size_t)bt * 32 + kt64) * 64 + k2lane;
            *reinterpret_cast<unsigned int*>(M5 + rec * 16 + g * 4) = pcode;
        }
    }
    #pragma unroll
    for (int off = 32; off > 0; off >>= 1)
        spikes += __shfl_down(spikes, off);
    if (lane == 0) sred[wv] = spikes;
    __syncthreads();
    if (tid == 0)
        atomicAdd(spike_count, (unsigned int)(sred[0] + sred[1] + sred[2] + sred[3]));
}

// ---------------- K2: layer 2 i8 K=64; p-code masks expanded via bank-replicated LUT -
// Stage per kt: {w2 8KB, pcodes 1KB} dbuf. LUT[22][32] at smem+18432: lane reads
// lut[p*32 + (lane&31)] -> always own bank, conflict-free. Repack masks into the
// wa/wb/w4 format so the A-build is unchanged (bit-exact vs round 17).
__global__ __launch_bounds__(256, 2) void k_layer2_i8(
    const unsigned char* __restrict__ M5,
    const signed char* __restrict__ W2q,
    const float* __restrict__ b2,
    float* __restrict__ out)
{
    __shared__ __align__(16) char smem[23040];   // [0,18432) stage 2x9216; [18432,21248) LUT; epi union
    float* sm_f32 = (float*)smem;
    unsigned* lut2 = (unsigned*)(smem + 18432);

    const int tid  = threadIdx.x;
    const int wv   = tid >> 6;
    const int tg   = wv;              // wave = t-group: t in [tg*5, tg*5+5)
    const int lane = tid & 63;
    const int l15  = lane & 15;
    const int g    = lane >> 4;
    const int b0   = blockIdx.x * 16;
    const int t0   = tg * 5;
    const int lsl  = lane & 31;

    for (int e = tid; e < 704; e += 256) {
        int p = e >> 5;
        unsigned m = 0;
        if (p >= 1)
            for (int t = p - 1; t < T_STEPS; t += p) m |= 1u << t;
        lut2[e] = m;
    }

    const size_t m5blk = (size_t)blockIdx.x * 32768;   // bytes

    i32x4 acc[8][5];
    #pragma unroll
    for (int n = 0; n < 8; ++n)
        #pragma unroll
        for (int t = 0; t < 5; ++t)
            acc[n][t] = (i32x4){0, 0, 0, 0};

    // prologue: stage kt=0 into buf 0. 9 chunks of 1KB: [0..7]=w2, [8]=pcodes
    for (int c = wv; c < 9; c += 4) {
        const char* s = (c < 8) ? ((const char*)W2q + c * 1024)
                                : ((const char*)M5 + m5blk);
        gl_lds16(s + lane * 16, smem + c * 1024);
    }

    for (int kt = 0; kt < 32; ++kt) {
        __syncthreads();
        const int cb = (kt & 1) * 9216;
        if (kt < 31) {
            const int nb = ((kt + 1) & 1) * 9216;
            for (int c = wv; c < 9; c += 4) {
                const char* s = (c < 8)
                    ? ((const char*)W2q + (size_t)(kt + 1) * 8192 + c * 1024)
                    : ((const char*)M5 + m5blk + (size_t)(kt + 1) * 1024);
                gl_lds16(s + lane * 16, smem + nb + c * 1024);
            }
        }

        uint4 pc = *reinterpret_cast<const uint4*>(smem + cb + 8192 + lane * 16);
        unsigned mk[16];
        #pragma unroll
        for (int j = 0; j < 4; ++j) {
            mk[j]      = lut2[(((pc.x >> (8 * j)) & 0xffu) << 5) | lsl];
            mk[4 + j]  = lut2[(((pc.y >> (8 * j)) & 0xffu) << 5) | lsl];
            mk[8 + j]  = lut2[(((pc.z >> (8 * j)) & 0xffu) << 5) | lsl];
            mk[12 + j] = lut2[(((pc.w >> (8 * j)) & 0xffu) << 5) | lsl];
        }
        uint4 wa, wb, w4;
        wa.x = (mk[0] & 0xffffu) | (mk[1] << 16);
        wa.y = (mk[2] & 0xffffu) | (mk[3] << 16);
        wa.z = (mk[4] & 0xffffu) | (mk[5] << 16);
        wa.w = (mk[6] & 0xffffu) | (mk[7] << 16);
        wb.x = (mk[8] & 0xffffu) | (mk[9] << 16);
        wb.y = (mk[10] & 0xffffu) | (mk[11] << 16);
        wb.z = (mk[12] & 0xffffu) | (mk[13] << 16);
        wb.w = (mk[14] & 0xffffu) | (mk[15] << 16);
        if (tg == 3) {
            w4.x = (mk[0] >> 16) | ((mk[1] >> 16) << 8) | ((mk[2] >> 16) << 16) | ((mk[3] >> 16) << 24);
            w4.y = (mk[4] >> 16) | ((mk[5] >> 16) << 8) | ((mk[6] >> 16) << 16) | ((mk[7] >> 16) << 24);
            w4.z = (mk[8] >> 16) | ((mk[9] >> 16) << 8) | ((mk[10] >> 16) << 16) | ((mk[11] >> 16) << 24);
            w4.w = (mk[12] >> 16) | ((mk[13] >> 16) << 8) | ((mk[14] >> 16) << 16) | ((mk[15] >> 16) << 24);
        } else {
            w4 = make_uint4(0u, 0u, 0u, 0u);
        }

        union { i32x4 v; unsigned u[4]; } A[5];
        #pragma unroll
        for (int tl = 0; tl < 5; ++tl) {
            const int t = t0 + tl;
            if (t < 16) {
                A[tl].u[0] = ((wa.x >> t) & 0x10001u) | (((wa.y >> t) & 0x10001u) << 8);
                A[tl].u[1] = ((wa.z >> t) & 0x10001u) | (((wa.w >> t) & 0x10001u) << 8);
                A[tl].u[2] = ((wb.x >> t) & 0x10001u) | (((wb.y >> t) & 0x10001u) << 8);
                A[tl].u[3] = ((wb.z >> t) & 0x10001u) | (((wb.w >> t) & 0x10001u) << 8);
            } else {
                const int tt = t - 16;
                A[tl].u[0] = __builtin_amdgcn_perm(0u, (w4.x >> tt) & 0x01010101u, 0x03010200u);
                A[tl].u[1] = __builtin_amdgcn_perm(0u, (w4.y >> tt) & 0x01010101u, 0x03010200u);
                A[tl].u[2] = __builtin_amdgcn_perm(0u, (w4.z >> tt) & 0x01010101u, 0x03010200u);
                A[tl].u[3] = __builtin_amdgcn_perm(0u, (w4.w >> tt) & 0x01010101u, 0x03010200u);
            }
        }

        i32x4 Bv[8];
        #pragma unroll
        for (int nt = 0; nt < 8; ++nt)
            Bv[nt] = *reinterpret_cast<const i32x4*>(smem + cb + nt * 1024 + lane * 16);
        #pragma unroll
        for (int tl = 0; tl < 5; ++tl)
            #pragma unroll
            for (int nt = 0; nt < 8; ++nt)
                acc[nt][tl] = __builtin_amdgcn_mfma_i32_16x16x64_i8(
                    A[tl].v, Bv[nt], acc[nt][tl], 0, 0, 0);
    }

    // epilogue: 8 chunks of 16 cols; transpose through LDS, then LIF per (b,c)
    #pragma unroll
    for (int q = 0; q < 8; ++q) {
        __syncthreads();
        #pragma unroll
        for (int tl = 0; tl < 5; ++tl)
            #pragma unroll
            for (int j = 0; j < 4; ++j)
                sm_f32[((g * 4 + j) * 17 + l15) * 21 + (t0 + tl)] = (float)acc[q][tl][j];
        __syncthreads();
        {
            const int bl  = tid >> 4;     // 0..15
            const int c16 = tid & 15;
            const int c   = q * 16 + c16;
            const float bias = b2[c];
            float u2 = 0.0f; int cnt = 0;
            #pragma unroll
            for (int t = 0; t < T_STEPS; ++t) {
                float X = __fadd_rn(__fmul_rn(sm_f32[(bl * 17 + c16) * 21 + t], 0.0009765625f), bias);
                u2 = __fadd_rn(__fmul_rn(0.9f, u2), X);
                if (u2 >= 1.0f) { cnt++; u2 = 0.0f; }
            }
            out[(size_t)(b0 + bl) * C_SZ + c] = (float)cnt / 20.0f;
        }
    }
}

// ---------------- K3: mean_spikes = total / (B * T) ----------------
__global__ void k_finalize(const unsigned int* __restrict__ spike_count, float* __restrict__ out) {
    out[(size_t)B_SZ * C_SZ] = (float)(*spike_count) / (float)((size_t)B_SZ * T_STEPS);
}

extern "C" void kernel_launch(void* const* d_in, const int* in_sizes, int n_in,
                              void* d_out, int out_size, void* d_ws, size_t ws_size,
                              hipStream_t stream) {
    const float* x  = (const float*)d_in[0];
    const float* W1 = (const float*)d_in[1];
    const float* b1 = (const float*)d_in[2];
    const float* W2 = (const float*)d_in[3];
    const float* b2 = (const float*)d_in[4];
    float* out = (float*)d_out;

    char* ws = (char*)d_ws;
    const size_t m5_b   = (size_t)B_SZ * H_SZ;       // 33.6 MB
    const size_t xfi_b  = (size_t)B_SZ * D_SZ;       // 16.8 MB
    const size_t w1fi_b = (size_t)H_SZ * D_SZ;       //  2.1 MB
    const size_t w2q_b  = (size_t)C_SZ * H_SZ;       //  0.26 MB

    size_t off = 0;
    unsigned char*  M5   = (unsigned char*)(ws + off);  off += m5_b;
    signed char*    xfi  = (signed char*)(ws + off);    off += xfi_b;
    signed char*    w1fi = (signed char*)(ws + off);    off += w1fi_b;
    signed char*    w2q  = (signed char*)(ws + off);    off += w2q_b;
    unsigned int* counter = (unsigned int*)(ws + off);  off += 256;

    hipMemsetAsync(counter, 0, sizeof(unsigned int), stream);

    k_w1fragi8<<<512, 256, 0, stream>>>(W1, w1fi);   // 131072 threads EXACT
    k_w2fragi8<<<64, 256, 0, stream>>>(W2, w2q);     // 16384 threads EXACT
    k_xfragi8<<<4096, 256, 0, stream>>>(x, xfi);     // 1048576 threads EXACT

    k_gemm1_i8<<<2048, 256, 0, stream>>>(xfi, w1fi, b1, M5, counter);

    k_layer2_i8<<<B_SZ / 16, 256, 0, stream>>>(M5, w2q, b2, out);

    k_finalize<<<1, 1, 0, stream>>>(counter, out);
}